// Round 13
// baseline (197.955 us; speedup 1.0000x reference)
//
#include <hip/hip_runtime.h>

// Involution via bf16 MFMA tap-GEMM, operand-swapped (D[t][px]).
// R12 fix: R11's permlane inline-asm was direction/aliasing-unsafe (wrong
// results). Now: __builtin_amdgcn_permlane{16,32}_swap (SSA, no aliasing)
// with the direction-agnostic pairsum identity
//   v[lane^K] = (out0 + out1) - v    (outputs' union is {even,odd} rows
// under either convention). __has_builtin fallback to __shfl_xor.

#define C_    256
#define HID_  64
#define KS_   7
#define KK_   49
#define G_    256
#define H_    64
#define W_    64
#define HW_   4096
#define BN_EPS 1e-5f

typedef __attribute__((ext_vector_type(8))) short bf16x8;
typedef __attribute__((ext_vector_type(4))) float f32x4;
typedef __attribute__((ext_vector_type(2))) unsigned uv2;

__device__ __forceinline__ ushort f2bf(float f) {
    unsigned u = __float_as_uint(f);
    return (ushort)((u + 0x7fffu + ((u >> 16) & 1u)) >> 16);   // RNE
}
__device__ __forceinline__ float bf2f(ushort s) {
    return __uint_as_float((unsigned)s << 16);
}
__device__ __forceinline__ float sel4(int l4, float a0, float a1, float a2, float a3) {
    float lo = (l4 & 1) ? a1 : a0;
    float hi = (l4 & 1) ? a3 : a2;
    return (l4 & 2) ? hi : lo;
}
// v[lane^16] on the VALU pipe, direction-agnostic (pairsum - own).
__device__ __forceinline__ float xor16p(float v) {
#if __has_builtin(__builtin_amdgcn_permlane16_swap)
    uv2 r = __builtin_amdgcn_permlane16_swap(__float_as_uint(v), __float_as_uint(v),
                                             false, false);
    return (__uint_as_float(r[0]) + __uint_as_float(r[1])) - v;
#else
    return __shfl_xor(v, 16);
#endif
}
// v[lane^32] on the VALU pipe, direction-agnostic.
__device__ __forceinline__ float xor32p(float v) {
#if __has_builtin(__builtin_amdgcn_permlane32_swap)
    uv2 r = __builtin_amdgcn_permlane32_swap(__float_as_uint(v), __float_as_uint(v),
                                             false, false);
    return (__uint_as_float(r[0]) + __uint_as_float(r[1])) - v;
#else
    return __shfl_xor(v, 32);
#endif
}
// sum across the 4 l4-groups of per-group partials v0..v3; lane gets pn=l4's total.
__device__ __forceinline__ float reduce4(int l4, float v0, float v1, float v2, float v3) {
    float own = sel4(l4, v0, v1, v2, v3);    // v[l4]
    float x1  = sel4(l4, v1, v0, v3, v2);    // v[l4^1]
    float x2_ = sel4(l4, v2, v3, v0, v1);    // v[l4^2]
    float x3  = sel4(l4, v3, v2, v1, v0);    // v[l4^3]
    float s1  = own + xor16p(x1);            // pn=l4 over {l4, l4^1}
    float s1c = x2_ + xor16p(x3);            // pn=l4^2 over {l4, l4^1}
    return s1 + xor32p(s1c);                 // + partner's pn=l4 over {l4^2,l4^3}
}

// ---------------------------------------------------------------- prep ----
// blocks 0..255:  kwb[g][t][k] bf16; skip u-rows {49,50,53,54,57,58,61,62}
// block 256:      rwT[k][o] = reduce_w[o][k]*bn_inv[o]; betp[o]
// block 257:      kbp[g][t] = bias (t<49), 0 elsewhere; skip {49,53,57,61}
// blocks 258+g:   kwb[g][{49,53,57,61}/{50,54,58,62}][k] = colsum hi/lo;
//                 kbp[g][{49,53,57,61}] = sum(kb)
__global__ __launch_bounds__(256) void prep_kernel(
    const float* __restrict__ kw, const float* __restrict__ kb,
    const float* __restrict__ reduce_w,
    const float* __restrict__ bn_gamma, const float* __restrict__ bn_beta,
    const float* __restrict__ bn_mean, const float* __restrict__ bn_var,
    ushort* __restrict__ kwb, float* __restrict__ rwT, float* __restrict__ betp,
    float* __restrict__ kbp)
{
    const int bid = blockIdx.x;
    if (bid < 256) {
        int idx  = bid * 256 + threadIdx.x;
        int base = idx * 16;
        int g    = base >> 12;
        int rem  = base & 4095;
        int t    = rem >> 6;
        int k0   = rem & 63;
        if (t >= 49 && ((t - 49) & 3) <= 1) return;   // u-rows
        union { ushort s[16]; uint4 v[2]; } u;
        if (t < KK_) {
            const float* src = kw + ((size_t)(g * KK_ + t)) * HID_ + k0;
            #pragma unroll
            for (int i = 0; i < 16; ++i) u.s[i] = f2bf(src[i]);
        } else {
            #pragma unroll
            for (int i = 0; i < 16; ++i) u.s[i] = 0;
        }
        uint4* dst = (uint4*)(kwb + base);
        dst[0] = u.v[0];
        dst[1] = u.v[1];
    } else if (bid == 256) {
        int k = threadIdx.x;
        #pragma unroll 1
        for (int o = 0; o < HID_; ++o) {
            float inv = bn_gamma[o] * rsqrtf(bn_var[o] + BN_EPS);
            rwT[k * HID_ + o] = reduce_w[o * C_ + k] * inv;
        }
        if (k < HID_) {
            float inv = bn_gamma[k] * rsqrtf(bn_var[k] + BN_EPS);
            betp[k] = bn_beta[k] - bn_mean[k] * inv;
        }
    } else if (bid == 257) {
        for (int i = threadIdx.x; i < G_ * 64; i += 256) {
            int g = i >> 6, t = i & 63;
            if (t >= 49 && ((t - 49) & 3) == 0) continue;  // bsum rows
            kbp[i] = (t < KK_) ? kb[g * KK_ + t] : 0.f;
        }
    } else {
        const int g = bid - 258;
        __shared__ float part[4][64];
        const int k  = threadIdx.x & 63;
        const int pr = threadIdx.x >> 6;
        const int t0 = pr * 13;
        const int t1 = (t0 + 13 < KK_) ? t0 + 13 : KK_;
        float s = 0.f;
        for (int t = t0; t < t1; ++t)
            s += kw[((size_t)(g * KK_ + t)) * HID_ + k];
        part[pr][k] = s;
        __syncthreads();
        if (threadIdx.x < 64) {
            float u = part[0][k] + part[1][k] + part[2][k] + part[3][k];
            ushort uh = f2bf(u);
            ushort ul = f2bf(u - bf2f(uh));
            #pragma unroll
            for (int rr = 0; rr < 4; ++rr) {
                kwb[(size_t)g * 4096 + (49 + rr * 4) * 64 + k] = uh;
                kwb[(size_t)g * 4096 + (50 + rr * 4) * 64 + k] = ul;
            }
            float bs = (k < KK_) ? kb[g * KK_ + k] : 0.f;
            #pragma unroll
            for (int off = 32; off >= 1; off >>= 1) bs += __shfl_xor(bs, off);
            if (k == 0) {
                #pragma unroll
                for (int rr = 0; rr < 4; ++rr) kbp[g * 64 + 49 + rr * 4] = bs;
            }
        }
    }
}

// ----------------------------------------------------------------- hv1 ----
__global__ __launch_bounds__(256) void hv1_kernel(
    const float* __restrict__ x, const float* __restrict__ rwT,
    float* __restrict__ hvp, int npx)
{
    const int lane = threadIdx.x & 63;
    const int wq   = __builtin_amdgcn_readfirstlane(threadIdx.x >> 6);
    const int kq   = blockIdx.y;
    const int p    = blockIdx.x * 64 + lane;
    const int b    = p >> 12;
    const int hw   = p & 4095;

    float acc[16];
    #pragma unroll
    for (int j = 0; j < 16; ++j) acc[j] = 0.f;

    const float* xp = x + ((size_t)b * C_ + kq * 64) * HW_ + hw;
    const float* rw = rwT + (kq * 64) * HID_ + wq * 16;
    #pragma unroll 8
    for (int kk = 0; kk < 64; ++kk) {
        float xk = xp[(size_t)kk * HW_];
        #pragma unroll
        for (int j = 0; j < 16; ++j) acc[j] = fmaf(xk, rw[kk * HID_ + j], acc[j]);
    }
    float* dst = hvp + ((size_t)(kq * 64 + wq * 16)) * npx + p;
    #pragma unroll
    for (int j = 0; j < 16; ++j) dst[(size_t)j * npx] = acc[j];
}

// ----------------------------------------------------------------- hv2 ----
__global__ __launch_bounds__(256) void hv2_kernel(
    const float* __restrict__ hvp, const float* __restrict__ betp,
    ushort* __restrict__ hv, int npx)
{
    const int p  = blockIdx.x * 256 + threadIdx.x;
    const int o0 = blockIdx.y * 4;
    ushort s[4];
    #pragma unroll
    for (int j = 0; j < 4; ++j) {
        float v = 0.f;
        #pragma unroll
        for (int kq = 0; kq < 4; ++kq)
            v += hvp[(size_t)(kq * 64 + o0 + j) * npx + p];
        s[j] = f2bf(fmaxf(v + betp[o0 + j], 0.f));
    }
    uint2 w;
    w.x = (uint)s[0] | ((uint)s[1] << 16);
    w.y = (uint)s[2] | ((uint)s[3] << 16);
    *(uint2*)(hv + (size_t)p * HID_ + o0) = w;
}

// ---------------------------------------------------------------- main ----
__global__ __launch_bounds__(256) void invol_main(
    const float* __restrict__ x, const ushort* __restrict__ hv,
    const ushort* __restrict__ kwb, const float* __restrict__ kbp,
    float* __restrict__ out)
{
    __shared__ float x_s[38][72];          // 10944 B, zero-padded window
    __shared__ float hs_s[38][64];         //  9728 B, horizontal 7-sums

    const int tid  = threadIdx.x;
    const int lane = tid & 63;
    const int wave = __builtin_amdgcn_readfirstlane(tid >> 6);
    const int bg   = blockIdx.x;           // b*G + g
    const int b    = bg >> 8;
    const int g    = bg & 255;
    const int y0   = blockIdx.y << 5;      // 0 or 32
    const int l15  = lane & 15;
    const int l4   = lane >> 4;

    // ---- stage x half-tile (zero-padded rows AND columns) ----
    const float* xg = x + (size_t)bg * HW_;
    for (int idx = tid; idx < 38 * 72; idx += 256) {
        int r = idx / 72, c = idx - r * 72;
        int yy = y0 - 3 + r;
        int cc = c - 3;
        bool v = ((unsigned)yy < 64u) && ((unsigned)cc < 64u);
        x_s[r][c] = v ? xg[yy * 64 + cc] : 0.f;
    }

    // ---- kw A-frags + bias, once per block ----
    bf16x8 ka[2][4];
    const char* kwg = (const char*)kwb + (size_t)g * 8192;
    #pragma unroll
    for (int ks = 0; ks < 2; ++ks)
        #pragma unroll
        for (int tm = 0; tm < 4; ++tm) {
            int byte = (tm * 16 + l15) * 128 + ks * 64 + l4 * 16;
            ka[ks][tm] = *(const bf16x8*)(kwg + byte);
        }
    f32x4 kv[4];
    #pragma unroll
    for (int tm = 0; tm < 4; ++tm)
        kv[tm] = *(const f32x4*)(kbp + g * 64 + tm * 16 + l4 * 4);

    // ---- per-lane tap geometry: t = tm*16 + l4*4 + r (t<48) ----
    int po[3][4];
    #pragma unroll
    for (int tm = 0; tm < 3; ++tm)
        #pragma unroll
        for (int r = 0; r < 4; ++r) {
            int t = tm * 16 + l4 * 4 + r;
            int i = (t * 147) >> 10;       // t/7 for t<64
            int j = t - i * 7;
            po[tm][r] = i * 72 + l15 + j;
        }
    const int po48 = 6 * 72 + l15 + 6;

    __syncthreads();

    // ---- h-pass: regs-first window load, slide in regs ----
    if (tid < 152) {
        int r  = tid >> 2;
        int c0 = (tid & 3) << 4;
        float v[22];
        #pragma unroll
        for (int i = 0; i < 22; ++i) v[i] = x_s[r][c0 + i];
        float s = v[0] + v[1] + v[2] + v[3] + v[4] + v[5] + v[6];
        hs_s[r][c0] = s;
        #pragma unroll
        for (int c = 1; c < 16; ++c) {
            s += v[c + 6] - v[c - 1];
            hs_s[r][c0 + c] = s;
        }
    }
    __syncthreads();

    const int rowpix0 = (b << 12) + (y0 << 6);

    #pragma unroll 2
    for (int rr = 0; rr < 8; ++rr) {
        const int ry = rr * 4 + wave;      // 0..31

        // hv B-frags for this row (only per-row global loads)
        bf16x8 hb[2][4];
        #pragma unroll
        for (int ks = 0; ks < 2; ++ks)
            #pragma unroll
            for (int pn = 0; pn < 4; ++pn) {
                const char* p = (const char*)(hv +
                    (size_t)(rowpix0 + (ry << 6) + pn * 16 + l15) * HID_)
                    + ks * 64 + l4 * 16;
                hb[ks][pn] = *(const bf16x8*)p;
            }

        // x2 window sum: 7 independent hs reads (overlaps the MFMAs)
        float x2 = hs_s[ry][lane] + hs_s[ry + 1][lane] + hs_s[ry + 2][lane]
                 + hs_s[ry + 3][lane] + hs_s[ry + 4][lane]
                 + hs_s[ry + 5][lane] + hs_s[ry + 6][lane];

        // acc init = bias (zero-padded taps get exactly 0)
        f32x4 acc[4][4];
        #pragma unroll
        for (int tm = 0; tm < 4; ++tm)
            #pragma unroll
            for (int pn = 0; pn < 4; ++pn) acc[tm][pn] = kv[tm];
        #pragma unroll
        for (int ks = 0; ks < 2; ++ks)
            #pragma unroll
            for (int tm = 0; tm < 4; ++tm)
                #pragma unroll
                for (int pn = 0; pn < 4; ++pn)
                    acc[tm][pn] = __builtin_amdgcn_mfma_f32_16x16x32_bf16(
                        ka[ks][tm], hb[ks][pn], acc[tm][pn], 0, 0, 0);

        // per-pn: ssq (in-lane partial), mean (in-lane via u-rows), kx partial
        float ssqp[4], mp[4], kxp[4];
        const float* xrow = &x_s[ry][0];
        #pragma unroll
        for (int pn = 0; pn < 4; ++pn) {
            float ssq = 0.f;
            #pragma unroll
            for (int tm = 0; tm < 3; ++tm)
                #pragma unroll
                for (int r = 0; r < 4; ++r) {
                    float e = acc[tm][pn][r];
                    ssq = fmaf(e, e, ssq);
                }
            float e48 = acc[3][pn][0];     // 0 on l4!=0 lanes
            ssqp[pn] = fmaf(e48, e48, ssq);
            mp[pn]  = (acc[3][pn][1] + acc[3][pn][2]) * (1.f / 49.f);
            kxp[pn] = 0.f;
        }
        #pragma unroll
        for (int tm = 0; tm < 3; ++tm)
            #pragma unroll
            for (int r = 0; r < 4; ++r) {
                const float* bp = xrow + po[tm][r];
                #pragma unroll
                for (int pn = 0; pn < 4; ++pn)
                    kxp[pn] = fmaf(acc[tm][pn][r], bp[pn * 16], kxp[pn]);
            }
        {
            const float* bp = xrow + po48;
            #pragma unroll
            for (int pn = 0; pn < 4; ++pn)
                kxp[pn] = fmaf(acc[3][pn][0], bp[pn * 16], kxp[pn]);
        }

        // VALU-pipe cross-lane reduces (permlane swaps via builtins)
        float kxo = reduce4(l4, kxp[0], kxp[1], kxp[2], kxp[3]);
        float sso = reduce4(l4, ssqp[0], ssqp[1], ssqp[2], ssqp[3]);
        float mo  = sel4(l4, mp[0], mp[1], mp[2], mp[3]);
        float ss  = fmaxf(sso - 49.f * mo * mo, 0.f);
        float is  = 1.f / fmaxf(sqrtf(ss), 1e-6f);
        out[(size_t)bg * HW_ + ((y0 + ry) << 6) + lane] = (kxo - mo * x2) * is;
    }
}

// --------------------------------------------- tier-2 hv (single-stage) ----
__global__ __launch_bounds__(256) void hv_kernel(
    const float* __restrict__ x, const float* __restrict__ rwT,
    const float* __restrict__ betp, ushort* __restrict__ hv)
{
    const int lane = threadIdx.x & 63;
    const int q    = __builtin_amdgcn_readfirstlane(threadIdx.x >> 6);
    const int p    = blockIdx.x * 64 + lane;
    const int b    = p >> 12;
    const int hw   = p & 4095;
    float acc[16];
    #pragma unroll
    for (int j = 0; j < 16; ++j) acc[j] = betp[q * 16 + j];
    const float* xp = x + (size_t)b * C_ * HW_ + hw;
    #pragma unroll 8
    for (int k = 0; k < C_; ++k) {
        float xk = xp[(size_t)k * HW_];
        const float* rw = rwT + k * HID_ + q * 16;
        #pragma unroll
        for (int j = 0; j < 16; ++j) acc[j] = fmaf(xk, rw[j], acc[j]);
    }
    union { ushort s[16]; uint4 v[2]; } u;
    #pragma unroll
    for (int j = 0; j < 16; ++j) u.s[j] = f2bf(fmaxf(acc[j], 0.f));
    uint4* dst = (uint4*)(hv + (size_t)p * HID_ + q * 16);
    dst[0] = u.v[0];
    dst[1] = u.v[1];
}

// ---------------------------------------------------- fallback (no ws) ----
__global__ __launch_bounds__(256) void invol_fallback(
    const float* __restrict__ x, const float* __restrict__ reduce_w,
    const float* __restrict__ bn_gamma, const float* __restrict__ bn_beta,
    const float* __restrict__ bn_mean, const float* __restrict__ bn_var,
    const float* __restrict__ kw, const float* __restrict__ kb,
    float* __restrict__ out)
{
    __shared__ float rwT[C_][HID_ + 4];
    __shared__ float bns[HID_];
    __shared__ float bnb[HID_];
    const int tid = threadIdx.x;
    const int b  = blockIdx.z;
    const int g0 = blockIdx.y * 32;
    const int p  = blockIdx.x * 256 + tid;
    const int py = p >> 6;
    const int px = p & 63;
    #pragma unroll 1
    for (int o = 0; o < HID_; ++o) rwT[tid][o] = reduce_w[o * C_ + tid];
    if (tid < HID_) {
        float inv = bn_gamma[tid] * rsqrtf(bn_var[tid] + BN_EPS);
        bns[tid] = inv;
        bnb[tid] = bn_beta[tid] - bn_mean[tid] * inv;
    }
    __syncthreads();
    float hvv[HID_];
    #pragma unroll
    for (int o = 0; o < HID_; ++o) hvv[o] = 0.f;
    const float* xb = x + (size_t)b * C_ * HW_ + p;
    #pragma unroll 4
    for (int k = 0; k < C_; ++k) {
        float xk = xb[(size_t)k * HW_];
        const float4* wr = (const float4*)&rwT[k][0];
        #pragma unroll
        for (int o4 = 0; o4 < HID_ / 4; ++o4) {
            float4 w = wr[o4];
            hvv[o4*4+0] = fmaf(xk, w.x, hvv[o4*4+0]);
            hvv[o4*4+1] = fmaf(xk, w.y, hvv[o4*4+1]);
            hvv[o4*4+2] = fmaf(xk, w.z, hvv[o4*4+2]);
            hvv[o4*4+3] = fmaf(xk, w.w, hvv[o4*4+3]);
        }
    }
    #pragma unroll
    for (int o = 0; o < HID_; ++o) hvv[o] = fmaxf(fmaf(hvv[o], bns[o], bnb[o]), 0.f);
    #pragma unroll 1
    for (int gi = 0; gi < 32; ++gi) {
        const int g = g0 + gi;
        const float* kwg = kw + (size_t)g * KK_ * HID_;
        float acc[KK_];
        #pragma unroll
        for (int t = 0; t < KK_; ++t) {
            float a = kb[g * KK_ + t];
            const float4* row = (const float4*)(kwg + t * HID_);
            #pragma unroll
            for (int k4 = 0; k4 < HID_ / 4; ++k4) {
                float4 w = row[k4];
                a = fmaf(w.x, hvv[k4*4+0], a);
                a = fmaf(w.y, hvv[k4*4+1], a);
                a = fmaf(w.z, hvv[k4*4+2], a);
                a = fmaf(w.w, hvv[k4*4+3], a);
            }
            acc[t] = a;
        }
        float mean = 0.f;
        #pragma unroll
        for (int t = 0; t < KK_; ++t) mean += acc[t];
        mean *= (1.f / 49.f);
        float ss = 0.f;
        #pragma unroll
        for (int t = 0; t < KK_; ++t) { acc[t] -= mean; ss = fmaf(acc[t], acc[t], ss); }
        float inv = 1.f / fmaxf(sqrtf(ss), 1e-6f);
        const float* xg = x + ((size_t)(b * G_ + g)) * HW_;
        float oacc = 0.f;
        #pragma unroll
        for (int i = 0; i < KS_; ++i) {
            int yv = py + i - 3;
            bool rok = ((unsigned)yv < (unsigned)H_);
            const float* xrow = xg + yv * W_;
            #pragma unroll
            for (int j = 0; j < KS_; ++j) {
                int xx = px + j - 3;
                bool ok = rok && ((unsigned)xx < (unsigned)W_);
                float v = ok ? xrow[xx] : 0.f;
                oacc = fmaf(v, acc[i*7+j], oacc);
            }
        }
        out[((size_t)(b * G_ + g)) * HW_ + p] = oacc * inv;
    }
}

extern "C" void kernel_launch(void* const* d_in, const int* in_sizes, int n_in,
                              void* d_out, int out_size, void* d_ws, size_t ws_size,
                              hipStream_t stream) {
    const float* x        = (const float*)d_in[0];
    const float* reduce_w = (const float*)d_in[1];
    const float* bn_gamma = (const float*)d_in[2];
    const float* bn_beta  = (const float*)d_in[3];
    const float* bn_mean  = (const float*)d_in[4];
    const float* bn_var   = (const float*)d_in[5];
    const float* kproj_w  = (const float*)d_in[6];
    const float* kproj_b  = (const float*)d_in[7];
    float* out = (float*)d_out;
    const int B   = in_sizes[0] / (C_ * HW_);
    const int npx = B * HW_;

    size_t kwb_off = 0;
    size_t kwb_sz  = (size_t)G_ * 64 * 64 * 2;        // 2 MB
    size_t kbp_off = kwb_off + kwb_sz;
    size_t kbp_sz  = (size_t)G_ * 64 * 4;             // 64 KB
    size_t rwt_off = kbp_off + kbp_sz;
    size_t rwt_sz  = (size_t)C_ * HID_ * 4;           // 64 KB
    size_t bet_off = rwt_off + rwt_sz;
    size_t bet_sz  = 256;
    size_t hv_off  = bet_off + bet_sz;
    size_t hv_sz   = (size_t)npx * HID_ * 2;          // 2 MB
    size_t hvp_off = hv_off + hv_sz;
    size_t hvp_sz  = (size_t)4 * HID_ * npx * 4;      // 16 MB
    size_t need2   = hvp_off;                          // without hvp
    size_t need    = hvp_off + hvp_sz;

    if (ws_size < need2) {
        dim3 grid(HW_ / 256, G_ / 32, B);
        invol_fallback<<<grid, 256, 0, stream>>>(x, reduce_w, bn_gamma, bn_beta,
                                                 bn_mean, bn_var, kproj_w, kproj_b, out);
        return;
    }

    ushort* kwb  = (ushort*)((char*)d_ws + kwb_off);
    float*  kbp  = (float*)((char*)d_ws + kbp_off);
    float*  rwT  = (float*)((char*)d_ws + rwt_off);
    float*  betp = (float*)((char*)d_ws + bet_off);
    ushort* hv   = (ushort*)((char*)d_ws + hv_off);
    float*  hvp  = (float*)((char*)d_ws + hvp_off);

    prep_kernel<<<dim3(258 + G_), 256, 0, stream>>>(kproj_w, kproj_b, reduce_w,
                                                    bn_gamma, bn_beta, bn_mean, bn_var,
                                                    kwb, rwT, betp, kbp);
    if (ws_size >= need) {
        hv1_kernel<<<dim3(npx / 64, 4), 256, 0, stream>>>(x, rwT, hvp, npx);
        hv2_kernel<<<dim3(npx / 256, 16), 256, 0, stream>>>(hvp, betp, hv, npx);
    } else {
        hv_kernel<<<dim3(npx / 64), 256, 0, stream>>>(x, rwT, betp, hv);
    }
    invol_main<<<dim3(B * G_, 2), 256, 0, stream>>>(x, hv, kwb, kbp, out);
}

// Round 14
// 197.398 us; speedup vs baseline: 1.0028x; 1.0028x over previous
//
#include <hip/hip_runtime.h>

// Involution via bf16 MFMA tap-GEMM, operand-swapped (D[t][px]).
// R12 fix: R11's permlane inline-asm was direction/aliasing-unsafe (wrong
// results). Now: __builtin_amdgcn_permlane{16,32}_swap (SSA, no aliasing)
// with the direction-agnostic pairsum identity
//   v[lane^K] = (out0 + out1) - v    (outputs' union is {even,odd} rows
// under either convention). __has_builtin fallback to __shfl_xor.

#define C_    256
#define HID_  64
#define KS_   7
#define KK_   49
#define G_    256
#define H_    64
#define W_    64
#define HW_   4096
#define BN_EPS 1e-5f

typedef __attribute__((ext_vector_type(8))) short bf16x8;
typedef __attribute__((ext_vector_type(4))) float f32x4;
typedef __attribute__((ext_vector_type(2))) unsigned uv2;

__device__ __forceinline__ ushort f2bf(float f) {
    unsigned u = __float_as_uint(f);
    return (ushort)((u + 0x7fffu + ((u >> 16) & 1u)) >> 16);   // RNE
}
__device__ __forceinline__ float bf2f(ushort s) {
    return __uint_as_float((unsigned)s << 16);
}
__device__ __forceinline__ float sel4(int l4, float a0, float a1, float a2, float a3) {
    float lo = (l4 & 1) ? a1 : a0;
    float hi = (l4 & 1) ? a3 : a2;
    return (l4 & 2) ? hi : lo;
}
// v[lane^16] on the VALU pipe, direction-agnostic (pairsum - own).
__device__ __forceinline__ float xor16p(float v) {
#if __has_builtin(__builtin_amdgcn_permlane16_swap)
    uv2 r = __builtin_amdgcn_permlane16_swap(__float_as_uint(v), __float_as_uint(v),
                                             false, false);
    return (__uint_as_float(r[0]) + __uint_as_float(r[1])) - v;
#else
    return __shfl_xor(v, 16);
#endif
}
// v[lane^32] on the VALU pipe, direction-agnostic.
__device__ __forceinline__ float xor32p(float v) {
#if __has_builtin(__builtin_amdgcn_permlane32_swap)
    uv2 r = __builtin_amdgcn_permlane32_swap(__float_as_uint(v), __float_as_uint(v),
                                             false, false);
    return (__uint_as_float(r[0]) + __uint_as_float(r[1])) - v;
#else
    return __shfl_xor(v, 32);
#endif
}
// sum across the 4 l4-groups of per-group partials v0..v3; lane gets pn=l4's total.
__device__ __forceinline__ float reduce4(int l4, float v0, float v1, float v2, float v3) {
    float own = sel4(l4, v0, v1, v2, v3);    // v[l4]
    float x1  = sel4(l4, v1, v0, v3, v2);    // v[l4^1]
    float x2_ = sel4(l4, v2, v3, v0, v1);    // v[l4^2]
    float x3  = sel4(l4, v3, v2, v1, v0);    // v[l4^3]
    float s1  = own + xor16p(x1);            // pn=l4 over {l4, l4^1}
    float s1c = x2_ + xor16p(x3);            // pn=l4^2 over {l4, l4^1}
    return s1 + xor32p(s1c);                 // + partner's pn=l4 over {l4^2,l4^3}
}

// ---------------------------------------------------------------- prep ----
// blocks 0..255:  kwb[g][t][k] bf16; skip u-rows {49,50,53,54,57,58,61,62}
// block 256:      rwT[k][o] = reduce_w[o][k]*bn_inv[o]; betp[o]
// block 257:      kbp[g][t] = bias (t<49), 0 elsewhere; skip {49,53,57,61}
// blocks 258+g:   kwb[g][{49,53,57,61}/{50,54,58,62}][k] = colsum hi/lo;
//                 kbp[g][{49,53,57,61}] = sum(kb)
__global__ __launch_bounds__(256) void prep_kernel(
    const float* __restrict__ kw, const float* __restrict__ kb,
    const float* __restrict__ reduce_w,
    const float* __restrict__ bn_gamma, const float* __restrict__ bn_beta,
    const float* __restrict__ bn_mean, const float* __restrict__ bn_var,
    ushort* __restrict__ kwb, float* __restrict__ rwT, float* __restrict__ betp,
    float* __restrict__ kbp)
{
    const int bid = blockIdx.x;
    if (bid < 256) {
        int idx  = bid * 256 + threadIdx.x;
        int base = idx * 16;
        int g    = base >> 12;
        int rem  = base & 4095;
        int t    = rem >> 6;
        int k0   = rem & 63;
        if (t >= 49 && ((t - 49) & 3) <= 1) return;   // u-rows
        union { ushort s[16]; uint4 v[2]; } u;
        if (t < KK_) {
            const float* src = kw + ((size_t)(g * KK_ + t)) * HID_ + k0;
            #pragma unroll
            for (int i = 0; i < 16; ++i) u.s[i] = f2bf(src[i]);
        } else {
            #pragma unroll
            for (int i = 0; i < 16; ++i) u.s[i] = 0;
        }
        uint4* dst = (uint4*)(kwb + base);
        dst[0] = u.v[0];
        dst[1] = u.v[1];
    } else if (bid == 256) {
        int k = threadIdx.x;
        #pragma unroll 1
        for (int o = 0; o < HID_; ++o) {
            float inv = bn_gamma[o] * rsqrtf(bn_var[o] + BN_EPS);
            rwT[k * HID_ + o] = reduce_w[o * C_ + k] * inv;
        }
        if (k < HID_) {
            float inv = bn_gamma[k] * rsqrtf(bn_var[k] + BN_EPS);
            betp[k] = bn_beta[k] - bn_mean[k] * inv;
        }
    } else if (bid == 257) {
        for (int i = threadIdx.x; i < G_ * 64; i += 256) {
            int g = i >> 6, t = i & 63;
            if (t >= 49 && ((t - 49) & 3) == 0) continue;  // bsum rows
            kbp[i] = (t < KK_) ? kb[g * KK_ + t] : 0.f;
        }
    } else {
        const int g = bid - 258;
        __shared__ float part[4][64];
        const int k  = threadIdx.x & 63;
        const int pr = threadIdx.x >> 6;
        const int t0 = pr * 13;
        const int t1 = (t0 + 13 < KK_) ? t0 + 13 : KK_;
        float s = 0.f;
        for (int t = t0; t < t1; ++t)
            s += kw[((size_t)(g * KK_ + t)) * HID_ + k];
        part[pr][k] = s;
        __syncthreads();
        if (threadIdx.x < 64) {
            float u = part[0][k] + part[1][k] + part[2][k] + part[3][k];
            ushort uh = f2bf(u);
            ushort ul = f2bf(u - bf2f(uh));
            #pragma unroll
            for (int rr = 0; rr < 4; ++rr) {
                kwb[(size_t)g * 4096 + (49 + rr * 4) * 64 + k] = uh;
                kwb[(size_t)g * 4096 + (50 + rr * 4) * 64 + k] = ul;
            }
            float bs = (k < KK_) ? kb[g * KK_ + k] : 0.f;
            #pragma unroll
            for (int off = 32; off >= 1; off >>= 1) bs += __shfl_xor(bs, off);
            if (k == 0) {
                #pragma unroll
                for (int rr = 0; rr < 4; ++rr) kbp[g * 64 + 49 + rr * 4] = bs;
            }
        }
    }
}

// ----------------------------------------------------------------- hv1 ----
__global__ __launch_bounds__(256) void hv1_kernel(
    const float* __restrict__ x, const float* __restrict__ rwT,
    float* __restrict__ hvp, int npx)
{
    const int lane = threadIdx.x & 63;
    const int wq   = __builtin_amdgcn_readfirstlane(threadIdx.x >> 6);
    const int kq   = blockIdx.y;
    const int p    = blockIdx.x * 64 + lane;
    const int b    = p >> 12;
    const int hw   = p & 4095;

    float acc[16];
    #pragma unroll
    for (int j = 0; j < 16; ++j) acc[j] = 0.f;

    const float* xp = x + ((size_t)b * C_ + kq * 64) * HW_ + hw;
    const float* rw = rwT + (kq * 64) * HID_ + wq * 16;
    #pragma unroll 8
    for (int kk = 0; kk < 64; ++kk) {
        float xk = xp[(size_t)kk * HW_];
        #pragma unroll
        for (int j = 0; j < 16; ++j) acc[j] = fmaf(xk, rw[kk * HID_ + j], acc[j]);
    }
    float* dst = hvp + ((size_t)(kq * 64 + wq * 16)) * npx + p;
    #pragma unroll
    for (int j = 0; j < 16; ++j) dst[(size_t)j * npx] = acc[j];
}

// ----------------------------------------------------------------- hv2 ----
__global__ __launch_bounds__(256) void hv2_kernel(
    const float* __restrict__ hvp, const float* __restrict__ betp,
    ushort* __restrict__ hv, int npx)
{
    const int p  = blockIdx.x * 256 + threadIdx.x;
    const int o0 = blockIdx.y * 4;
    ushort s[4];
    #pragma unroll
    for (int j = 0; j < 4; ++j) {
        float v = 0.f;
        #pragma unroll
        for (int kq = 0; kq < 4; ++kq)
            v += hvp[(size_t)(kq * 64 + o0 + j) * npx + p];
        s[j] = f2bf(fmaxf(v + betp[o0 + j], 0.f));
    }
    uint2 w;
    w.x = (uint)s[0] | ((uint)s[1] << 16);
    w.y = (uint)s[2] | ((uint)s[3] << 16);
    *(uint2*)(hv + (size_t)p * HID_ + o0) = w;
}

// ---------------------------------------------------------------- main ----
__global__ __launch_bounds__(256) void invol_main(
    const float* __restrict__ x, const ushort* __restrict__ hv,
    const ushort* __restrict__ kwb, const float* __restrict__ kbp,
    float* __restrict__ out)
{
    __shared__ float x_s[38][72];          // 10944 B, zero-padded window
    __shared__ float hs_s[38][64];         //  9728 B, horizontal 7-sums

    const int tid  = threadIdx.x;
    const int lane = tid & 63;
    const int wave = __builtin_amdgcn_readfirstlane(tid >> 6);
    const int bg   = blockIdx.x;           // b*G + g
    const int b    = bg >> 8;
    const int g    = bg & 255;
    const int y0   = blockIdx.y << 5;      // 0 or 32
    const int l15  = lane & 15;
    const int l4   = lane >> 4;

    // ---- stage x half-tile (zero-padded rows AND columns) ----
    const float* xg = x + (size_t)bg * HW_;
    for (int idx = tid; idx < 38 * 72; idx += 256) {
        int r = idx / 72, c = idx - r * 72;
        int yy = y0 - 3 + r;
        int cc = c - 3;
        bool v = ((unsigned)yy < 64u) && ((unsigned)cc < 64u);
        x_s[r][c] = v ? xg[yy * 64 + cc] : 0.f;
    }

    // ---- kw A-frags + bias, once per block ----
    bf16x8 ka[2][4];
    const char* kwg = (const char*)kwb + (size_t)g * 8192;
    #pragma unroll
    for (int ks = 0; ks < 2; ++ks)
        #pragma unroll
        for (int tm = 0; tm < 4; ++tm) {
            int byte = (tm * 16 + l15) * 128 + ks * 64 + l4 * 16;
            ka[ks][tm] = *(const bf16x8*)(kwg + byte);
        }
    f32x4 kv[4];
    #pragma unroll
    for (int tm = 0; tm < 4; ++tm)
        kv[tm] = *(const f32x4*)(kbp + g * 64 + tm * 16 + l4 * 4);

    // ---- per-lane tap geometry: t = tm*16 + l4*4 + r (t<48) ----
    int po[3][4];
    #pragma unroll
    for (int tm = 0; tm < 3; ++tm)
        #pragma unroll
        for (int r = 0; r < 4; ++r) {
            int t = tm * 16 + l4 * 4 + r;
            int i = (t * 147) >> 10;       // t/7 for t<64
            int j = t - i * 7;
            po[tm][r] = i * 72 + l15 + j;
        }
    const int po48 = 6 * 72 + l15 + 6;

    __syncthreads();

    // ---- h-pass: regs-first window load, slide in regs ----
    if (tid < 152) {
        int r  = tid >> 2;
        int c0 = (tid & 3) << 4;
        float v[22];
        #pragma unroll
        for (int i = 0; i < 22; ++i) v[i] = x_s[r][c0 + i];
        float s = v[0] + v[1] + v[2] + v[3] + v[4] + v[5] + v[6];
        hs_s[r][c0] = s;
        #pragma unroll
        for (int c = 1; c < 16; ++c) {
            s += v[c + 6] - v[c - 1];
            hs_s[r][c0 + c] = s;
        }
    }
    __syncthreads();

    const int rowpix0 = (b << 12) + (y0 << 6);

    #pragma unroll 2
    for (int rr = 0; rr < 8; ++rr) {
        const int ry = rr * 4 + wave;      // 0..31

        // hv B-frags for this row (only per-row global loads)
        bf16x8 hb[2][4];
        #pragma unroll
        for (int ks = 0; ks < 2; ++ks)
            #pragma unroll
            for (int pn = 0; pn < 4; ++pn) {
                const char* p = (const char*)(hv +
                    (size_t)(rowpix0 + (ry << 6) + pn * 16 + l15) * HID_)
                    + ks * 64 + l4 * 16;
                hb[ks][pn] = *(const bf16x8*)p;
            }

        // x2 window sum: 7 independent hs reads (overlaps the MFMAs)
        float x2 = hs_s[ry][lane] + hs_s[ry + 1][lane] + hs_s[ry + 2][lane]
                 + hs_s[ry + 3][lane] + hs_s[ry + 4][lane]
                 + hs_s[ry + 5][lane] + hs_s[ry + 6][lane];

        // acc init = bias (zero-padded taps get exactly 0)
        f32x4 acc[4][4];
        #pragma unroll
        for (int tm = 0; tm < 4; ++tm)
            #pragma unroll
            for (int pn = 0; pn < 4; ++pn) acc[tm][pn] = kv[tm];
        #pragma unroll
        for (int ks = 0; ks < 2; ++ks)
            #pragma unroll
            for (int tm = 0; tm < 4; ++tm)
                #pragma unroll
                for (int pn = 0; pn < 4; ++pn)
                    acc[tm][pn] = __builtin_amdgcn_mfma_f32_16x16x32_bf16(
                        ka[ks][tm], hb[ks][pn], acc[tm][pn], 0, 0, 0);

        // per-pn: ssq (in-lane partial), mean (in-lane via u-rows), kx partial
        float ssqp[4], mp[4], kxp[4];
        const float* xrow = &x_s[ry][0];
        #pragma unroll
        for (int pn = 0; pn < 4; ++pn) {
            float ssq = 0.f;
            #pragma unroll
            for (int tm = 0; tm < 3; ++tm)
                #pragma unroll
                for (int r = 0; r < 4; ++r) {
                    float e = acc[tm][pn][r];
                    ssq = fmaf(e, e, ssq);
                }
            float e48 = acc[3][pn][0];     // 0 on l4!=0 lanes
            ssqp[pn] = fmaf(e48, e48, ssq);
            mp[pn]  = (acc[3][pn][1] + acc[3][pn][2]) * (1.f / 49.f);
            kxp[pn] = 0.f;
        }
        #pragma unroll
        for (int tm = 0; tm < 3; ++tm)
            #pragma unroll
            for (int r = 0; r < 4; ++r) {
                const float* bp = xrow + po[tm][r];
                #pragma unroll
                for (int pn = 0; pn < 4; ++pn)
                    kxp[pn] = fmaf(acc[tm][pn][r], bp[pn * 16], kxp[pn]);
            }
        {
            const float* bp = xrow + po48;
            #pragma unroll
            for (int pn = 0; pn < 4; ++pn)
                kxp[pn] = fmaf(acc[3][pn][0], bp[pn * 16], kxp[pn]);
        }

        // VALU-pipe cross-lane reduces (permlane swaps via builtins)
        float kxo = reduce4(l4, kxp[0], kxp[1], kxp[2], kxp[3]);
        float sso = reduce4(l4, ssqp[0], ssqp[1], ssqp[2], ssqp[3]);
        float mo  = sel4(l4, mp[0], mp[1], mp[2], mp[3]);
        float ss  = fmaxf(sso - 49.f * mo * mo, 0.f);
        float is  = 1.f / fmaxf(sqrtf(ss), 1e-6f);
        out[(size_t)bg * HW_ + ((y0 + ry) << 6) + lane] = (kxo - mo * x2) * is;
    }
}

// --------------------------------------------- tier-2 hv (single-stage) ----
__global__ __launch_bounds__(256) void hv_kernel(
    const float* __restrict__ x, const float* __restrict__ rwT,
    const float* __restrict__ betp, ushort* __restrict__ hv)
{
    const int lane = threadIdx.x & 63;
    const int q    = __builtin_amdgcn_readfirstlane(threadIdx.x >> 6);
    const int p    = blockIdx.x * 64 + lane;
    const int b    = p >> 12;
    const int hw   = p & 4095;
    float acc[16];
    #pragma unroll
    for (int j = 0; j < 16; ++j) acc[j] = betp[q * 16 + j];
    const float* xp = x + (size_t)b * C_ * HW_ + hw;
    #pragma unroll 8
    for (int k = 0; k < C_; ++k) {
        float xk = xp[(size_t)k * HW_];
        const float* rw = rwT + k * HID_ + q * 16;
        #pragma unroll
        for (int j = 0; j < 16; ++j) acc[j] = fmaf(xk, rw[j], acc[j]);
    }
    union { ushort s[16]; uint4 v[2]; } u;
    #pragma unroll
    for (int j = 0; j < 16; ++j) u.s[j] = f2bf(fmaxf(acc[j], 0.f));
    uint4* dst = (uint4*)(hv + (size_t)p * HID_ + q * 16);
    dst[0] = u.v[0];
    dst[1] = u.v[1];
}

// ---------------------------------------------------- fallback (no ws) ----
__global__ __launch_bounds__(256) void invol_fallback(
    const float* __restrict__ x, const float* __restrict__ reduce_w,
    const float* __restrict__ bn_gamma, const float* __restrict__ bn_beta,
    const float* __restrict__ bn_mean, const float* __restrict__ bn_var,
    const float* __restrict__ kw, const float* __restrict__ kb,
    float* __restrict__ out)
{
    __shared__ float rwT[C_][HID_ + 4];
    __shared__ float bns[HID_];
    __shared__ float bnb[HID_];
    const int tid = threadIdx.x;
    const int b  = blockIdx.z;
    const int g0 = blockIdx.y * 32;
    const int p  = blockIdx.x * 256 + tid;
    const int py = p >> 6;
    const int px = p & 63;
    #pragma unroll 1
    for (int o = 0; o < HID_; ++o) rwT[tid][o] = reduce_w[o * C_ + tid];
    if (tid < HID_) {
        float inv = bn_gamma[tid] * rsqrtf(bn_var[tid] + BN_EPS);
        bns[tid] = inv;
        bnb[tid] = bn_beta[tid] - bn_mean[tid] * inv;
    }
    __syncthreads();
    float hvv[HID_];
    #pragma unroll
    for (int o = 0; o < HID_; ++o) hvv[o] = 0.f;
    const float* xb = x + (size_t)b * C_ * HW_ + p;
    #pragma unroll 4
    for (int k = 0; k < C_; ++k) {
        float xk = xb[(size_t)k * HW_];
        const float4* wr = (const float4*)&rwT[k][0];
        #pragma unroll
        for (int o4 = 0; o4 < HID_ / 4; ++o4) {
            float4 w = wr[o4];
            hvv[o4*4+0] = fmaf(xk, w.x, hvv[o4*4+0]);
            hvv[o4*4+1] = fmaf(xk, w.y, hvv[o4*4+1]);
            hvv[o4*4+2] = fmaf(xk, w.z, hvv[o4*4+2]);
            hvv[o4*4+3] = fmaf(xk, w.w, hvv[o4*4+3]);
        }
    }
    #pragma unroll
    for (int o = 0; o < HID_; ++o) hvv[o] = fmaxf(fmaf(hvv[o], bns[o], bnb[o]), 0.f);
    #pragma unroll 1
    for (int gi = 0; gi < 32; ++gi) {
        const int g = g0 + gi;
        const float* kwg = kw + (size_t)g * KK_ * HID_;
        float acc[KK_];
        #pragma unroll
        for (int t = 0; t < KK_; ++t) {
            float a = kb[g * KK_ + t];
            const float4* row = (const float4*)(kwg + t * HID_);
            #pragma unroll
            for (int k4 = 0; k4 < HID_ / 4; ++k4) {
                float4 w = row[k4];
                a = fmaf(w.x, hvv[k4*4+0], a);
                a = fmaf(w.y, hvv[k4*4+1], a);
                a = fmaf(w.z, hvv[k4*4+2], a);
                a = fmaf(w.w, hvv[k4*4+3], a);
            }
            acc[t] = a;
        }
        float mean = 0.f;
        #pragma unroll
        for (int t = 0; t < KK_; ++t) mean += acc[t];
        mean *= (1.f / 49.f);
        float ss = 0.f;
        #pragma unroll
        for (int t = 0; t < KK_; ++t) { acc[t] -= mean; ss = fmaf(acc[t], acc[t], ss); }
        float inv = 1.f / fmaxf(sqrtf(ss), 1e-6f);
        const float* xg = x + ((size_t)(b * G_ + g)) * HW_;
        float oacc = 0.f;
        #pragma unroll
        for (int i = 0; i < KS_; ++i) {
            int yv = py + i - 3;
            bool rok = ((unsigned)yv < (unsigned)H_);
            const float* xrow = xg + yv * W_;
            #pragma unroll
            for (int j = 0; j < KS_; ++j) {
                int xx = px + j - 3;
                bool ok = rok && ((unsigned)xx < (unsigned)W_);
                float v = ok ? xrow[xx] : 0.f;
                oacc = fmaf(v, acc[i*7+j], oacc);
            }
        }
        out[((size_t)(b * G_ + g)) * HW_ + p] = oacc * inv;
    }
}

extern "C" void kernel_launch(void* const* d_in, const int* in_sizes, int n_in,
                              void* d_out, int out_size, void* d_ws, size_t ws_size,
                              hipStream_t stream) {
    const float* x        = (const float*)d_in[0];
    const float* reduce_w = (const float*)d_in[1];
    const float* bn_gamma = (const float*)d_in[2];
    const float* bn_beta  = (const float*)d_in[3];
    const float* bn_mean  = (const float*)d_in[4];
    const float* bn_var   = (const float*)d_in[5];
    const float* kproj_w  = (const float*)d_in[6];
    const float* kproj_b  = (const float*)d_in[7];
    float* out = (float*)d_out;
    const int B   = in_sizes[0] / (C_ * HW_);
    const int npx = B * HW_;

    size_t kwb_off = 0;
    size_t kwb_sz  = (size_t)G_ * 64 * 64 * 2;        // 2 MB
    size_t kbp_off = kwb_off + kwb_sz;
    size_t kbp_sz  = (size_t)G_ * 64 * 4;             // 64 KB
    size_t rwt_off = kbp_off + kbp_sz;
    size_t rwt_sz  = (size_t)C_ * HID_ * 4;           // 64 KB
    size_t bet_off = rwt_off + rwt_sz;
    size_t bet_sz  = 256;
    size_t hv_off  = bet_off + bet_sz;
    size_t hv_sz   = (size_t)npx * HID_ * 2;          // 2 MB
    size_t hvp_off = hv_off + hv_sz;
    size_t hvp_sz  = (size_t)4 * HID_ * npx * 4;      // 16 MB
    size_t need2   = hvp_off;                          // without hvp
    size_t need    = hvp_off + hvp_sz;

    if (ws_size < need2) {
        dim3 grid(HW_ / 256, G_ / 32, B);
        invol_fallback<<<grid, 256, 0, stream>>>(x, reduce_w, bn_gamma, bn_beta,
                                                 bn_mean, bn_var, kproj_w, kproj_b, out);
        return;
    }

    ushort* kwb  = (ushort*)((char*)d_ws + kwb_off);
    float*  kbp  = (float*)((char*)d_ws + kbp_off);
    float*  rwT  = (float*)((char*)d_ws + rwt_off);
    float*  betp = (float*)((char*)d_ws + bet_off);
    ushort* hv   = (ushort*)((char*)d_ws + hv_off);
    float*  hvp  = (float*)((char*)d_ws + hvp_off);

    prep_kernel<<<dim3(258 + G_), 256, 0, stream>>>(kproj_w, kproj_b, reduce_w,
                                                    bn_gamma, bn_beta, bn_mean, bn_var,
                                                    kwb, rwT, betp, kbp);
    if (ws_size >= need) {
        hv1_kernel<<<dim3(npx / 64, 4), 256, 0, stream>>>(x, rwT, hvp, npx);
        hv2_kernel<<<dim3(npx / 256, 16), 256, 0, stream>>>(hvp, betp, hv, npx);
    } else {
        hv_kernel<<<dim3(npx / 64), 256, 0, stream>>>(x, rwT, betp, hv);
    }
    invol_main<<<dim3(B * G_, 2), 256, 0, stream>>>(x, hv, kwb, kbp, out);
}

// Round 15
// 130.867 us; speedup vs baseline: 1.5126x; 1.5084x over previous
//
#include <hip/hip_runtime.h>

// Involution via bf16 MFMA tap-GEMM, operand-swapped (D[t][px]).
// R15: 32x32x16 MFMA relayout. D-layout (verified m74/m101): col=lane&31,
// row=(reg&3)+8*(reg>>2)+4*(lane>>5). Lane holds 32 of 64 tap-rows for one
// pixel column; complement in lane^32 -> ssq/kx reduce = ONE xor32 each
// (R14-proven pairsum permlane builtin). Mean fully in-lane via u-row
// replication at regs 9/10 (prep's {49,53,57,61}/{50,54,58,62} lands there
// for both lane halves). Zero tap rows excluded at compile time.

#define C_    256
#define HID_  64
#define KS_   7
#define KK_   49
#define G_    256
#define H_    64
#define W_    64
#define HW_   4096
#define BN_EPS 1e-5f

typedef __attribute__((ext_vector_type(8)))  short bf16x8;
typedef __attribute__((ext_vector_type(4)))  float f32x4;
typedef __attribute__((ext_vector_type(16))) float f32x16;
typedef __attribute__((ext_vector_type(2)))  unsigned uv2;

__device__ __forceinline__ ushort f2bf(float f) {
    unsigned u = __float_as_uint(f);
    return (ushort)((u + 0x7fffu + ((u >> 16) & 1u)) >> 16);   // RNE
}
__device__ __forceinline__ float bf2f(ushort s) {
    return __uint_as_float((unsigned)s << 16);
}
// v[lane^32] on the VALU pipe, direction-agnostic (pairsum - own). Proven R14.
__device__ __forceinline__ float xor32p(float v) {
#if __has_builtin(__builtin_amdgcn_permlane32_swap)
    uv2 r = __builtin_amdgcn_permlane32_swap(__float_as_uint(v), __float_as_uint(v),
                                             false, false);
    return (__uint_as_float(r[0]) + __uint_as_float(r[1])) - v;
#else
    return __shfl_xor(v, 32);
#endif
}

// ---------------------------------------------------------------- prep ----
// blocks 0..255:  kwb[g][t][k] bf16; skip u-rows {49,50,53,54,57,58,61,62}
// block 256:      rwT[k][o] = reduce_w[o][k]*bn_inv[o]; betp[o]
// block 257:      kbp[g][t] = bias (t<49), 0 elsewhere; skip {49,53,57,61}
// blocks 258+g:   kwb[g][{49,53,57,61}/{50,54,58,62}][k] = colsum hi/lo;
//                 kbp[g][{49,53,57,61}] = sum(kb)
__global__ __launch_bounds__(256) void prep_kernel(
    const float* __restrict__ kw, const float* __restrict__ kb,
    const float* __restrict__ reduce_w,
    const float* __restrict__ bn_gamma, const float* __restrict__ bn_beta,
    const float* __restrict__ bn_mean, const float* __restrict__ bn_var,
    ushort* __restrict__ kwb, float* __restrict__ rwT, float* __restrict__ betp,
    float* __restrict__ kbp)
{
    const int bid = blockIdx.x;
    if (bid < 256) {
        int idx  = bid * 256 + threadIdx.x;
        int base = idx * 16;
        int g    = base >> 12;
        int rem  = base & 4095;
        int t    = rem >> 6;
        int k0   = rem & 63;
        if (t >= 49 && ((t - 49) & 3) <= 1) return;   // u-rows
        union { ushort s[16]; uint4 v[2]; } u;
        if (t < KK_) {
            const float* src = kw + ((size_t)(g * KK_ + t)) * HID_ + k0;
            #pragma unroll
            for (int i = 0; i < 16; ++i) u.s[i] = f2bf(src[i]);
        } else {
            #pragma unroll
            for (int i = 0; i < 16; ++i) u.s[i] = 0;
        }
        uint4* dst = (uint4*)(kwb + base);
        dst[0] = u.v[0];
        dst[1] = u.v[1];
    } else if (bid == 256) {
        int k = threadIdx.x;
        #pragma unroll 1
        for (int o = 0; o < HID_; ++o) {
            float inv = bn_gamma[o] * rsqrtf(bn_var[o] + BN_EPS);
            rwT[k * HID_ + o] = reduce_w[o * C_ + k] * inv;
        }
        if (k < HID_) {
            float inv = bn_gamma[k] * rsqrtf(bn_var[k] + BN_EPS);
            betp[k] = bn_beta[k] - bn_mean[k] * inv;
        }
    } else if (bid == 257) {
        for (int i = threadIdx.x; i < G_ * 64; i += 256) {
            int g = i >> 6, t = i & 63;
            if (t >= 49 && ((t - 49) & 3) == 0) continue;  // bsum rows
            kbp[i] = (t < KK_) ? kb[g * KK_ + t] : 0.f;
        }
    } else {
        const int g = bid - 258;
        __shared__ float part[4][64];
        const int k  = threadIdx.x & 63;
        const int pr = threadIdx.x >> 6;
        const int t0 = pr * 13;
        const int t1 = (t0 + 13 < KK_) ? t0 + 13 : KK_;
        float s = 0.f;
        for (int t = t0; t < t1; ++t)
            s += kw[((size_t)(g * KK_ + t)) * HID_ + k];
        part[pr][k] = s;
        __syncthreads();
        if (threadIdx.x < 64) {
            float u = part[0][k] + part[1][k] + part[2][k] + part[3][k];
            ushort uh = f2bf(u);
            ushort ul = f2bf(u - bf2f(uh));
            #pragma unroll
            for (int rr = 0; rr < 4; ++rr) {
                kwb[(size_t)g * 4096 + (49 + rr * 4) * 64 + k] = uh;
                kwb[(size_t)g * 4096 + (50 + rr * 4) * 64 + k] = ul;
            }
            float bs = (k < KK_) ? kb[g * KK_ + k] : 0.f;
            #pragma unroll
            for (int off = 32; off >= 1; off >>= 1) bs += __shfl_xor(bs, off);
            if (k == 0) {
                #pragma unroll
                for (int rr = 0; rr < 4; ++rr) kbp[g * 64 + 49 + rr * 4] = bs;
            }
        }
    }
}

// ----------------------------------------------------------------- hv1 ----
__global__ __launch_bounds__(256) void hv1_kernel(
    const float* __restrict__ x, const float* __restrict__ rwT,
    float* __restrict__ hvp, int npx)
{
    const int lane = threadIdx.x & 63;
    const int wq   = __builtin_amdgcn_readfirstlane(threadIdx.x >> 6);
    const int kq   = blockIdx.y;
    const int p    = blockIdx.x * 64 + lane;
    const int b    = p >> 12;
    const int hw   = p & 4095;

    float acc[16];
    #pragma unroll
    for (int j = 0; j < 16; ++j) acc[j] = 0.f;

    const float* xp = x + ((size_t)b * C_ + kq * 64) * HW_ + hw;
    const float* rw = rwT + (kq * 64) * HID_ + wq * 16;
    #pragma unroll 8
    for (int kk = 0; kk < 64; ++kk) {
        float xk = xp[(size_t)kk * HW_];
        #pragma unroll
        for (int j = 0; j < 16; ++j) acc[j] = fmaf(xk, rw[kk * HID_ + j], acc[j]);
    }
    float* dst = hvp + ((size_t)(kq * 64 + wq * 16)) * npx + p;
    #pragma unroll
    for (int j = 0; j < 16; ++j) dst[(size_t)j * npx] = acc[j];
}

// ----------------------------------------------------------------- hv2 ----
__global__ __launch_bounds__(256) void hv2_kernel(
    const float* __restrict__ hvp, const float* __restrict__ betp,
    ushort* __restrict__ hv, int npx)
{
    const int p  = blockIdx.x * 256 + threadIdx.x;
    const int o0 = blockIdx.y * 4;
    ushort s[4];
    #pragma unroll
    for (int j = 0; j < 4; ++j) {
        float v = 0.f;
        #pragma unroll
        for (int kq = 0; kq < 4; ++kq)
            v += hvp[(size_t)(kq * 64 + o0 + j) * npx + p];
        s[j] = f2bf(fmaxf(v + betp[o0 + j], 0.f));
    }
    uint2 w;
    w.x = (uint)s[0] | ((uint)s[1] << 16);
    w.y = (uint)s[2] | ((uint)s[3] << 16);
    *(uint2*)(hv + (size_t)p * HID_ + o0) = w;
}

// ---------------------------------------------------------------- main ----
// Block = (b, g, half). 32x32x16 MFMA: D[t][px], 2 M-tiles x 2 N-tiles.
__global__ __launch_bounds__(256) void invol_main(
    const float* __restrict__ x, const ushort* __restrict__ hv,
    const ushort* __restrict__ kwb, const float* __restrict__ kbp,
    float* __restrict__ out)
{
    __shared__ float x_s[38][72];          // 10944 B, zero-padded window
    __shared__ float hs_s[38][64];         //  9728 B, horizontal 7-sums

    const int tid  = threadIdx.x;
    const int lane = tid & 63;
    const int wave = __builtin_amdgcn_readfirstlane(tid >> 6);
    const int bg   = blockIdx.x;           // b*G + g
    const int b    = bg >> 8;
    const int g    = bg & 255;
    const int y0   = blockIdx.y << 5;      // 0 or 32
    const int l31  = lane & 31;
    const int h4   = (lane >> 5) * 4;      // row offset of this lane half
    const int kl16 = (lane >> 5) * 16;     // k byte offset of this lane half

    // ---- stage x half-tile (zero-padded rows AND columns) ----
    const float* xg = x + (size_t)bg * HW_;
    for (int idx = tid; idx < 38 * 72; idx += 256) {
        int r = idx / 72, c = idx - r * 72;
        int yy = y0 - 3 + r;
        int cc = c - 3;
        bool v = ((unsigned)yy < 64u) && ((unsigned)cc < 64u);
        x_s[r][c] = v ? xg[yy * 64 + cc] : 0.f;
    }

    // ---- kw A-frags (2 M-tiles x 4 k-steps) + bias, once per block ----
    bf16x8 ka[2][4];
    const char* kwg = (const char*)kwb + (size_t)g * 8192;
    #pragma unroll
    for (int m = 0; m < 2; ++m)
        #pragma unroll
        for (int s = 0; s < 4; ++s)
            ka[m][s] = *(const bf16x8*)(kwg + (m * 32 + l31) * 128 + s * 32 + kl16);
    // bias per (m, reg-quad): t = m*32 + q*8 + h4 + e
    f32x4 kv[2][4];
    #pragma unroll
    for (int m = 0; m < 2; ++m)
        #pragma unroll
        for (int q = 0; q < 4; ++q)
            kv[m][q] = *(const f32x4*)(kbp + g * 64 + m * 32 + q * 8 + h4);

    // ---- per-lane tap offsets (row-relative): t = m*32+(r&3)+8*(r>>2)+h4 ----
    int po0[16], po1[9];
    #pragma unroll
    for (int r = 0; r < 16; ++r) {
        int T = (r & 3) + 8 * (r >> 2) + h4;
        int i = (T * 147) >> 10;           // T/7 for T<64
        int j = T - i * 7;
        po0[r] = i * 72 + j + l31;
    }
    #pragma unroll
    for (int r = 0; r < 9; ++r) {
        int T = 32 + (r & 3) + 8 * (r >> 2) + h4;
        int i = (T * 147) >> 10;
        int j = T - i * 7;
        po1[r] = i * 72 + j + l31;
    }

    __syncthreads();

    // ---- h-pass: regs-first window load, slide in regs ----
    if (tid < 152) {
        int r  = tid >> 2;
        int c0 = (tid & 3) << 4;
        float v[22];
        #pragma unroll
        for (int i = 0; i < 22; ++i) v[i] = x_s[r][c0 + i];
        float s = v[0] + v[1] + v[2] + v[3] + v[4] + v[5] + v[6];
        hs_s[r][c0] = s;
        #pragma unroll
        for (int c = 1; c < 16; ++c) {
            s += v[c + 6] - v[c - 1];
            hs_s[r][c0 + c] = s;
        }
    }
    __syncthreads();

    const int rowpix0 = (b << 12) + (y0 << 6);

    #pragma unroll 2
    for (int rr = 0; rr < 8; ++rr) {
        const int ry = rr * 4 + wave;      // 0..31

        // hv B-frags for this row: 2 N-tiles x 4 k-steps
        bf16x8 hb0[4], hb1[4];
        const char* hvrow = (const char*)hv + (size_t)(rowpix0 + (ry << 6)) * 128;
        #pragma unroll
        for (int s = 0; s < 4; ++s) {
            hb0[s] = *(const bf16x8*)(hvrow + l31 * 128 + s * 32 + kl16);
            hb1[s] = *(const bf16x8*)(hvrow + (32 + l31) * 128 + s * 32 + kl16);
        }

        // x2 window sum for own pixel (col = lane)
        float x2 = hs_s[ry][lane] + hs_s[ry + 1][lane] + hs_s[ry + 2][lane]
                 + hs_s[ry + 3][lane] + hs_s[ry + 4][lane]
                 + hs_s[ry + 5][lane] + hs_s[ry + 6][lane];

        // acc init = bias (zero tap rows get exactly 0)
        f32x16 acc00, acc01, acc10, acc11;
        #pragma unroll
        for (int q = 0; q < 4; ++q)
            #pragma unroll
            for (int e = 0; e < 4; ++e) {
                acc00[q * 4 + e] = kv[0][q][e];
                acc01[q * 4 + e] = kv[0][q][e];
                acc10[q * 4 + e] = kv[1][q][e];
                acc11[q * 4 + e] = kv[1][q][e];
            }
        #pragma unroll
        for (int s = 0; s < 4; ++s) {
            acc00 = __builtin_amdgcn_mfma_f32_32x32x16_bf16(ka[0][s], hb0[s], acc00, 0, 0, 0);
            acc01 = __builtin_amdgcn_mfma_f32_32x32x16_bf16(ka[0][s], hb1[s], acc01, 0, 0, 0);
            acc10 = __builtin_amdgcn_mfma_f32_32x32x16_bf16(ka[1][s], hb0[s], acc10, 0, 0, 0);
            acc11 = __builtin_amdgcn_mfma_f32_32x32x16_bf16(ka[1][s], hb1[s], acc11, 0, 0, 0);
        }

        // ssq partials per N-tile (M-tile1: regs 0..8 only; 9,10,13,14 = u-rows,
        // 11,12,15 = zero rows)
        float ssq0 = 0.f, ssq1 = 0.f;
        #pragma unroll
        for (int r = 0; r < 16; ++r) {
            ssq0 = fmaf(acc00[r], acc00[r], ssq0);
            ssq1 = fmaf(acc01[r], acc01[r], ssq1);
        }
        #pragma unroll
        for (int r = 0; r < 9; ++r) {
            ssq0 = fmaf(acc10[r], acc10[r], ssq0);
            ssq1 = fmaf(acc11[r], acc11[r], ssq1);
        }
        // mean fully in-lane (u-rows at regs 9,10 of M-tile1 for both halves)
        float mn0 = (acc10[9] + acc10[10]) * (1.f / 49.f);
        float mn1 = (acc11[9] + acc11[10]) * (1.f / 49.f);

        // kx partials: LDS reads at po + 32*n
        float kx0 = 0.f, kx1 = 0.f;
        const float* xb = &x_s[0][0] + ry * 72;
        #pragma unroll
        for (int r = 0; r < 16; ++r) {
            float xv0 = xb[po0[r]];
            float xv1 = xb[po0[r] + 32];
            kx0 = fmaf(acc00[r], xv0, kx0);
            kx1 = fmaf(acc01[r], xv1, kx1);
        }
        #pragma unroll
        for (int r = 0; r < 9; ++r) {
            float xv0 = xb[po1[r]];
            float xv1 = xb[po1[r] + 32];
            kx0 = fmaf(acc10[r], xv0, kx0);
            kx1 = fmaf(acc11[r], xv1, kx1);
        }

        // own/cross select + ONE xor32 per quantity
        const bool lo = lane < 32;
        float kx_own = lo ? kx0 : kx1, kx_cr = lo ? kx1 : kx0;
        float ss_own = lo ? ssq0 : ssq1, ss_cr = lo ? ssq1 : ssq0;
        float mo     = lo ? mn0 : mn1;
        float kxo = kx_own + xor32p(kx_cr);
        float sso = ss_own + xor32p(ss_cr);

        float ss = fmaxf(sso - 49.f * mo * mo, 0.f);
        float is = 1.f / fmaxf(sqrtf(ss), 1e-6f);
        out[(size_t)bg * HW_ + ((y0 + ry) << 6) + lane] = (kxo - mo * x2) * is;
    }
}

// --------------------------------------------- tier-2 hv (single-stage) ----
__global__ __launch_bounds__(256) void hv_kernel(
    const float* __restrict__ x, const float* __restrict__ rwT,
    const float* __restrict__ betp, ushort* __restrict__ hv)
{
    const int lane = threadIdx.x & 63;
    const int q    = __builtin_amdgcn_readfirstlane(threadIdx.x >> 6);
    const int p    = blockIdx.x * 64 + lane;
    const int b    = p >> 12;
    const int hw   = p & 4095;
    float acc[16];
    #pragma unroll
    for (int j = 0; j < 16; ++j) acc[j] = betp[q * 16 + j];
    const float* xp = x + (size_t)b * C_ * HW_ + hw;
    #pragma unroll 8
    for (int k = 0; k < C_; ++k) {
        float xk = xp[(size_t)k * HW_];
        const float* rw = rwT + k * HID_ + q * 16;
        #pragma unroll
        for (int j = 0; j < 16; ++j) acc[j] = fmaf(xk, rw[j], acc[j]);
    }
    union { ushort s[16]; uint4 v[2]; } u;
    #pragma unroll
    for (int j = 0; j < 16; ++j) u.s[j] = f2bf(fmaxf(acc[j], 0.f));
    uint4* dst = (uint4*)(hv + (size_t)p * HID_ + q * 16);
    dst[0] = u.v[0];
    dst[1] = u.v[1];
}

// ---------------------------------------------------- fallback (no ws) ----
__global__ __launch_bounds__(256) void invol_fallback(
    const float* __restrict__ x, const float* __restrict__ reduce_w,
    const float* __restrict__ bn_gamma, const float* __restrict__ bn_beta,
    const float* __restrict__ bn_mean, const float* __restrict__ bn_var,
    const float* __restrict__ kw, const float* __restrict__ kb,
    float* __restrict__ out)
{
    __shared__ float rwT[C_][HID_ + 4];
    __shared__ float bns[HID_];
    __shared__ float bnb[HID_];
    const int tid = threadIdx.x;
    const int b  = blockIdx.z;
    const int g0 = blockIdx.y * 32;
    const int p  = blockIdx.x * 256 + tid;
    const int py = p >> 6;
    const int px = p & 63;
    #pragma unroll 1
    for (int o = 0; o < HID_; ++o) rwT[tid][o] = reduce_w[o * C_ + tid];
    if (tid < HID_) {
        float inv = bn_gamma[tid] * rsqrtf(bn_var[tid] + BN_EPS);
        bns[tid] = inv;
        bnb[tid] = bn_beta[tid] - bn_mean[tid] * inv;
    }
    __syncthreads();
    float hvv[HID_];
    #pragma unroll
    for (int o = 0; o < HID_; ++o) hvv[o] = 0.f;
    const float* xb = x + (size_t)b * C_ * HW_ + p;
    #pragma unroll 4
    for (int k = 0; k < C_; ++k) {
        float xk = xb[(size_t)k * HW_];
        const float4* wr = (const float4*)&rwT[k][0];
        #pragma unroll
        for (int o4 = 0; o4 < HID_ / 4; ++o4) {
            float4 w = wr[o4];
            hvv[o4*4+0] = fmaf(xk, w.x, hvv[o4*4+0]);
            hvv[o4*4+1] = fmaf(xk, w.y, hvv[o4*4+1]);
            hvv[o4*4+2] = fmaf(xk, w.z, hvv[o4*4+2]);
            hvv[o4*4+3] = fmaf(xk, w.w, hvv[o4*4+3]);
        }
    }
    #pragma unroll
    for (int o = 0; o < HID_; ++o) hvv[o] = fmaxf(fmaf(hvv[o], bns[o], bnb[o]), 0.f);
    #pragma unroll 1
    for (int gi = 0; gi < 32; ++gi) {
        const int g = g0 + gi;
        const float* kwg = kw + (size_t)g * KK_ * HID_;
        float acc[KK_];
        #pragma unroll
        for (int t = 0; t < KK_; ++t) {
            float a = kb[g * KK_ + t];
            const float4* row = (const float4*)(kwg + t * HID_);
            #pragma unroll
            for (int k4 = 0; k4 < HID_ / 4; ++k4) {
                float4 w = row[k4];
                a = fmaf(w.x, hvv[k4*4+0], a);
                a = fmaf(w.y, hvv[k4*4+1], a);
                a = fmaf(w.z, hvv[k4*4+2], a);
                a = fmaf(w.w, hvv[k4*4+3], a);
            }
            acc[t] = a;
        }
        float mean = 0.f;
        #pragma unroll
        for (int t = 0; t < KK_; ++t) mean += acc[t];
        mean *= (1.f / 49.f);
        float ss = 0.f;
        #pragma unroll
        for (int t = 0; t < KK_; ++t) { acc[t] -= mean; ss = fmaf(acc[t], acc[t], ss); }
        float inv = 1.f / fmaxf(sqrtf(ss), 1e-6f);
        const float* xg = x + ((size_t)(b * G_ + g)) * HW_;
        float oacc = 0.f;
        #pragma unroll
        for (int i = 0; i < KS_; ++i) {
            int yv = py + i - 3;
            bool rok = ((unsigned)yv < (unsigned)H_);
            const float* xrow = xg + yv * W_;
            #pragma unroll
            for (int j = 0; j < KS_; ++j) {
                int xx = px + j - 3;
                bool ok = rok && ((unsigned)xx < (unsigned)W_);
                float v = ok ? xrow[xx] : 0.f;
                oacc = fmaf(v, acc[i*7+j], oacc);
            }
        }
        out[((size_t)(b * G_ + g)) * HW_ + p] = oacc * inv;
    }
}

extern "C" void kernel_launch(void* const* d_in, const int* in_sizes, int n_in,
                              void* d_out, int out_size, void* d_ws, size_t ws_size,
                              hipStream_t stream) {
    const float* x        = (const float*)d_in[0];
    const float* reduce_w = (const float*)d_in[1];
    const float* bn_gamma = (const float*)d_in[2];
    const float* bn_beta  = (const float*)d_in[3];
    const float* bn_mean  = (const float*)d_in[4];
    const float* bn_var   = (const float*)d_in[5];
    const float* kproj_w  = (const float*)d_in[6];
    const float* kproj_b  = (const float*)d_in[7];
    float* out = (float*)d_out;
    const int B   = in_sizes[0] / (C_ * HW_);
    const int npx = B * HW_;

    size_t kwb_off = 0;
    size_t kwb_sz  = (size_t)G_ * 64 * 64 * 2;        // 2 MB
    size_t kbp_off = kwb_off + kwb_sz;
    size_t kbp_sz  = (size_t)G_ * 64 * 4;             // 64 KB
    size_t rwt_off = kbp_off + kbp_sz;
    size_t rwt_sz  = (size_t)C_ * HID_ * 4;           // 64 KB
    size_t bet_off = rwt_off + rwt_sz;
    size_t bet_sz  = 256;
    size_t hv_off  = bet_off + bet_sz;
    size_t hv_sz   = (size_t)npx * HID_ * 2;          // 2 MB
    size_t hvp_off = hv_off + hv_sz;
    size_t hvp_sz  = (size_t)4 * HID_ * npx * 4;      // 16 MB
    size_t need2   = hvp_off;                          // without hvp
    size_t need    = hvp_off + hvp_sz;

    if (ws_size < need2) {
        dim3 grid(HW_ / 256, G_ / 32, B);
        invol_fallback<<<grid, 256, 0, stream>>>(x, reduce_w, bn_gamma, bn_beta,
                                                 bn_mean, bn_var, kproj_w, kproj_b, out);
        return;
    }

    ushort* kwb  = (ushort*)((char*)d_ws + kwb_off);
    float*  kbp  = (float*)((char*)d_ws + kbp_off);
    float*  rwT  = (float*)((char*)d_ws + rwt_off);
    float*  betp = (float*)((char*)d_ws + bet_off);
    ushort* hv   = (ushort*)((char*)d_ws + hv_off);
    float*  hvp  = (float*)((char*)d_ws + hvp_off);

    prep_kernel<<<dim3(258 + G_), 256, 0, stream>>>(kproj_w, kproj_b, reduce_w,
                                                    bn_gamma, bn_beta, bn_mean, bn_var,
                                                    kwb, rwT, betp, kbp);
    if (ws_size >= need) {
        hv1_kernel<<<dim3(npx / 64, 4), 256, 0, stream>>>(x, rwT, hvp, npx);
        hv2_kernel<<<dim3(npx / 256, 16), 256, 0, stream>>>(hvp, betp, hv, npx);
    } else {
        hv_kernel<<<dim3(npx / 64), 256, 0, stream>>>(x, rwT, betp, hv);
    }
    invol_main<<<dim3(B * G_, 2), 256, 0, stream>>>(x, hv, kwb, kbp, out);
}